// Round 3
// baseline (399.555 us; speedup 1.0000x reference)
//
#include <hip/hip_runtime.h>
#include <math.h>

// Problem constants (match reference)
constexpr int N   = 1024;
constexpr int D   = 128;
constexpr int S   = 200;
constexpr int D2  = D / 2;            // float2 elements per row
constexpr int ND2 = N * D2;           // per-step noise stride in float2
constexpr int CHAIN_BLOCKS = (N * D2) / 256;   // 256 blocks own the chains
constexpr int SEG = 8;                // k-segments for phase 2
constexpr int L   = S / SEG;          // 25 steps per segment
constexpr int PF1 = 10;               // phase-1 prefetch depth (S % PF1 == 0)
constexpr int PF2 = 5;                // phase-2 prefetch depth (L % PF2 == 0)
constexpr int PF  = 8;                // fallback kernel prefetch (S % PF == 0)

// clang builtin vector types — required by __builtin_nontemporal_{load,store}
typedef float f2 __attribute__((ext_vector_type(2)));
typedef float f4 __attribute__((ext_vector_type(4)));

// ---------------------------------------------------------------------------
// Phase 1: sequential x-scan over all 200 steps, storing x at segment
// boundaries (every L steps) into workspace. Read-only streaming of the
// 100 MB noise (regular loads -> stays L3-resident for phase 2).
// x-update arithmetic is IDENTICAL to phase 2 -> bit-identical results.
// ---------------------------------------------------------------------------
__global__ __launch_bounds__(256, 4) void boundary_kernel(
    const f2* __restrict__ x0,
    const f2* __restrict__ mean,
    const f2* __restrict__ var,
    const float* __restrict__ gammas,
    const f2* __restrict__ noise,   // [S][N][D2]
    f2* __restrict__ bnd)           // [SEG-1][N][D2]
{
    __shared__ float sg[S];
    __shared__ float ss[S];
    for (int i = threadIdx.x; i < S; i += 256) {
        float g = gammas[i];
        sg[i] = g;
        ss[i] = sqrtf(2.0f * g);
    }
    __syncthreads();

    const int idx = blockIdx.x * 256 + threadIdx.x;  // 0 .. N*D2-1
    const int dp  = idx & 63;

    f2 x        = x0[idx];
    const f2 m  = mean[dp];
    const f2 v  = var[dp];
    const float ivx = 1.0f / v.x;
    const float ivy = 1.0f / v.y;

    const f2* zp = noise + idx;

    f2 zb[PF1];
    #pragma unroll
    for (int i = 0; i < PF1; ++i) zb[i] = zp[(size_t)i * ND2];

    #pragma unroll 1
    for (int kb = 0; kb < S; kb += PF1) {
        f2 zn[PF1];
        if (kb + PF1 < S) {
            #pragma unroll
            for (int i = 0; i < PF1; ++i)
                zn[i] = zp[(size_t)(kb + PF1 + i) * ND2];
        }
        #pragma unroll
        for (int i = 0; i < PF1; ++i) {
            const int k = kb + i;
            const float g = sg[k];
            const float s = ss[k];
            const float gx = g * ivx;
            const float gy = g * ivy;
            // same op sequence as segment_kernel: tox then fma with z
            x.x = fmaf(s, zb[i].x, fmaf(-gx, x.x - m.x, x.x));
            x.y = fmaf(s, zb[i].y, fmaf(-gy, x.y - m.y, x.y));
            if (((k + 1) % L) == 0 && (k + 1) < S)
                bnd[(size_t)((k + 1) / L - 1) * ND2 + idx] = x;
        }
        #pragma unroll
        for (int i = 0; i < PF1; ++i) zb[i] = zn[i];
    }
}

// ---------------------------------------------------------------------------
// Phase 2: SEG x 256 chain blocks, each replays one 25-step segment from its
// boundary value (noise reads are L3-warm), plus 1024 y/steps writer blocks.
// 6 blocks/CU resident -> 24 waves/CU vs 4 before.
// ---------------------------------------------------------------------------
__global__ __launch_bounds__(256, 6) void segment_kernel(
    const f2* __restrict__ x0,
    const f4* __restrict__ y0,
    const f2* __restrict__ mean,
    const f2* __restrict__ var,
    const float* __restrict__ gammas,
    const f2* __restrict__ noise,   // [S][N][D2]
    const f2* __restrict__ bnd,     // [SEG-1][N][D2]
    f2* __restrict__ x_tot,         // [N][S][D2]
    f4* __restrict__ y_tot,         // [N][S][D/4]
    f2* __restrict__ outp,          // [N][S][D2]
    float* __restrict__ steps)      // [N][S]
{
    if (blockIdx.x >= SEG * CHAIN_BLOCKS) {
        // ---------- y / steps writer: one block per sample n ----------
        const int n   = blockIdx.x - SEG * CHAIN_BLOCKS;
        const int t   = threadIdx.x;
        const int col = t & 31;         // float4 column 0..31 (32*4 = 128 floats)
        const int r0  = t >> 5;         // row-group 0..7
        const f4  yv  = y0[(size_t)n * 32 + col];
        f4* yq = y_tot + (size_t)n * (S * 32);
        #pragma unroll
        for (int j = 0; j < S / 8; ++j) {
            const int k = r0 + j * 8;
            __builtin_nontemporal_store(yv, &yq[(size_t)k * 32 + col]);
        }
        if (t < S) steps[(size_t)n * S + t] = (float)t;
        return;
    }

    __shared__ float sg[L];
    __shared__ float ss[L];
    const int seg = blockIdx.x / CHAIN_BLOCKS;
    const int rb  = blockIdx.x % CHAIN_BLOCKS;
    const int k0  = seg * L;
    if (threadIdx.x < L) {
        float g = gammas[k0 + threadIdx.x];
        sg[threadIdx.x] = g;
        ss[threadIdx.x] = sqrtf(2.0f * g);
    }
    __syncthreads();

    const int idx = rb * 256 + threadIdx.x;          // 0 .. N*D2-1
    const int n   = idx >> 6;
    const int dp  = idx & 63;

    f2 x = (seg == 0) ? x0[idx] : bnd[(size_t)(seg - 1) * ND2 + idx];
    const f2 m  = mean[dp];
    const f2 v  = var[dp];
    const float ivx = 1.0f / v.x;
    const float ivy = 1.0f / v.y;

    const f2* zp = noise + (size_t)k0 * ND2 + idx;
    f2* xq = x_tot + (size_t)n * (S * D2) + (size_t)k0 * D2 + dp;
    f2* oq = outp  + (size_t)n * (S * D2) + (size_t)k0 * D2 + dp;

    f2 zb[PF2];
    #pragma unroll
    for (int i = 0; i < PF2; ++i) zb[i] = zp[(size_t)i * ND2];

    #pragma unroll 1
    for (int kb = 0; kb < L; kb += PF2) {
        f2 zn[PF2];
        if (kb + PF2 < L) {
            #pragma unroll
            for (int i = 0; i < PF2; ++i)
                zn[i] = zp[(size_t)(kb + PF2 + i) * ND2];
        }
        #pragma unroll
        for (int i = 0; i < PF2; ++i) {
            const int k = kb + i;
            const float g = sg[k];
            const float s = ss[k];
            const float gx = g * ivx;
            const float gy = g * ivy;

            const float tox = fmaf(-gx, x.x - m.x, x.x);
            const float toy = fmaf(-gy, x.y - m.y, x.y);
            x.x = fmaf(s, zb[i].x, tox);
            x.y = fmaf(s, zb[i].y, toy);
            const float tnx = fmaf(-gx, x.x - m.x, x.x);
            const float tny = fmaf(-gy, x.y - m.y, x.y);

            f2 o;
            o.x = tox - tnx;
            o.y = toy - tny;

            __builtin_nontemporal_store(x, &xq[(size_t)k * D2]);
            __builtin_nontemporal_store(o, &oq[(size_t)k * D2]);
        }
        #pragma unroll
        for (int i = 0; i < PF2; ++i) zb[i] = zn[i];
    }
}

// ---------------------------------------------------------------------------
// Fallback: round-2 single-phase kernel (used only if ws_size is too small).
// ---------------------------------------------------------------------------
__global__ __launch_bounds__(256, 4) void langevin_kernel(
    const f2* __restrict__ x0,
    const f4* __restrict__ y0,
    const f2* __restrict__ mean,
    const f2* __restrict__ var,
    const float* __restrict__ gammas,
    const f2* __restrict__ noise,
    f2* __restrict__ x_tot,
    f4* __restrict__ y_tot,
    f2* __restrict__ outp,
    float* __restrict__ steps)
{
    if (blockIdx.x >= CHAIN_BLOCKS) {
        const int n   = blockIdx.x - CHAIN_BLOCKS;
        const int t   = threadIdx.x;
        const int col = t & 31;
        const int r0  = t >> 5;
        const f4  yv  = y0[(size_t)n * 32 + col];
        f4* yq = y_tot + (size_t)n * (S * 32);
        #pragma unroll
        for (int j = 0; j < S / 8; ++j) {
            const int k = r0 + j * 8;
            __builtin_nontemporal_store(yv, &yq[(size_t)k * 32 + col]);
        }
        if (t < S) steps[(size_t)n * S + t] = (float)t;
        return;
    }

    __shared__ float sg[S];
    __shared__ float ss[S];
    for (int i = threadIdx.x; i < S; i += 256) {
        float g = gammas[i];
        sg[i] = g;
        ss[i] = sqrtf(2.0f * g);
    }
    __syncthreads();

    const int idx = blockIdx.x * 256 + threadIdx.x;
    const int n   = idx >> 6;
    const int dp  = idx & 63;

    f2 x        = x0[idx];
    const f2 m  = mean[dp];
    const f2 v  = var[dp];
    const float ivx = 1.0f / v.x;
    const float ivy = 1.0f / v.y;

    const f2* zp = noise + idx;
    f2* xq = x_tot + (size_t)n * (S * D2) + dp;
    f2* oq = outp  + (size_t)n * (S * D2) + dp;

    f2 zb[PF];
    #pragma unroll
    for (int i = 0; i < PF; ++i)
        zb[i] = __builtin_nontemporal_load(&zp[(size_t)i * ND2]);

    #pragma unroll 1
    for (int kb = 0; kb < S; kb += PF) {
        f2 zn[PF];
        if (kb + PF < S) {
            #pragma unroll
            for (int i = 0; i < PF; ++i)
                zn[i] = __builtin_nontemporal_load(&zp[(size_t)(kb + PF + i) * ND2]);
        }
        #pragma unroll
        for (int i = 0; i < PF; ++i) {
            const int k = kb + i;
            const float g = sg[k];
            const float s = ss[k];
            const float gx = g * ivx;
            const float gy = g * ivy;

            const float tox = fmaf(-gx, x.x - m.x, x.x);
            const float toy = fmaf(-gy, x.y - m.y, x.y);
            x.x = fmaf(s, zb[i].x, tox);
            x.y = fmaf(s, zb[i].y, toy);
            const float tnx = fmaf(-gx, x.x - m.x, x.x);
            const float tny = fmaf(-gy, x.y - m.y, x.y);

            f2 o;
            o.x = tox - tnx;
            o.y = toy - tny;

            __builtin_nontemporal_store(x, &xq[(size_t)k * D2]);
            __builtin_nontemporal_store(o, &oq[(size_t)k * D2]);
        }
        #pragma unroll
        for (int i = 0; i < PF; ++i) zb[i] = zn[i];
    }
}

extern "C" void kernel_launch(void* const* d_in, const int* in_sizes, int n_in,
                              void* d_out, int out_size, void* d_ws, size_t ws_size,
                              hipStream_t stream)
{
    const float* x0     = (const float*)d_in[0];
    const float* y0     = (const float*)d_in[1];
    const float* mean   = (const float*)d_in[2];
    const float* var    = (const float*)d_in[3];
    const float* gammas = (const float*)d_in[4];
    const float* noise  = (const float*)d_in[5];

    float* x_tot = (float*)d_out;                       // N*S*D
    float* y_tot = x_tot + (size_t)N * S * D;           // N*S*D
    float* outp  = y_tot + (size_t)N * S * D;           // N*S*D
    float* steps = outp  + (size_t)N * S * D;           // N*S

    const size_t need = (size_t)(SEG - 1) * ND2 * sizeof(f2);   // ~3.7 MB
    if (d_ws != nullptr && ws_size >= need) {
        boundary_kernel<<<CHAIN_BLOCKS, 256, 0, stream>>>(
            (const f2*)x0, (const f2*)mean, (const f2*)var, gammas,
            (const f2*)noise, (f2*)d_ws);
        segment_kernel<<<SEG * CHAIN_BLOCKS + N, 256, 0, stream>>>(
            (const f2*)x0, (const f4*)y0, (const f2*)mean, (const f2*)var,
            gammas, (const f2*)noise, (const f2*)d_ws,
            (f2*)x_tot, (f4*)y_tot, (f2*)outp, steps);
    } else {
        langevin_kernel<<<CHAIN_BLOCKS + N, 256, 0, stream>>>(
            (const f2*)x0, (const f4*)y0, (const f2*)mean, (const f2*)var,
            gammas, (const f2*)noise,
            (f2*)x_tot, (f4*)y_tot, (f2*)outp, steps);
    }
}